// Round 1
// baseline (569.927 us; speedup 1.0000x reference)
//
#include <hip/hip_runtime.h>
#include <hip/hip_bf16.h>
#include <stdint.h>

typedef unsigned short ushort_t;
typedef unsigned int uint_t;

// Problem sizes (fixed by reference)
#define BB 16
#define TT 2048
#define DD 1024
#define HH 1024
#define MM (BB * TT)   // 32768
#define NN (3 * HH)    // 3072
#define KK DD          // 1024
#define NCHUNK 32
#define CLEN (TT / NCHUNK)  // 64

typedef __bf16 bf16x8 __attribute__((ext_vector_type(8)));
typedef float floatx4 __attribute__((ext_vector_type(4)));

// ---------- helpers ----------
__device__ __forceinline__ ushort_t f2b(float f) {
  union { float f; uint_t u; } v; v.f = f;
  uint_t u = v.u;
  uint_t r = (u + 0x7FFFu + ((u >> 16) & 1u)) >> 16;  // RNE
  return (ushort_t)r;
}
__device__ __forceinline__ float b2f_lo(uint_t u) {
  union { uint_t u; float f; } v; v.u = u << 16; return v.f;
}
__device__ __forceinline__ float b2f_hi(uint_t u) {
  union { uint_t u; float f; } v; v.u = u & 0xFFFF0000u; return v.f;
}
__device__ __forceinline__ float fast_sigmoid(float x) {
  return 1.0f / (1.0f + __expf(-x));
}
__device__ __forceinline__ float fast_tanh(float x) {
  x = fminf(fmaxf(x, -15.0f), 15.0f);
  float e = __expf(2.0f * x);
  return (e - 1.0f) / (e + 1.0f);
}

// async global->LDS, 16B per lane, dst = wave-uniform base + lane*16
__device__ __forceinline__ void async_ld16(const void* g, void* l) {
  auto gp = (const __attribute__((address_space(1))) unsigned int*)(uintptr_t)g;
  unsigned loff = (unsigned)(uintptr_t)l;  // generic LDS ptr low 32 bits = LDS addr
  auto lp = (__attribute__((address_space(3))) unsigned int*)loff;
  __builtin_amdgcn_global_load_lds(gp, lp, 16, 0, 0);
}

// ---------- kernel 1: x fp32 -> bf16 ----------
__global__ __launch_bounds__(256) void cvt_x_kernel(const float4* __restrict__ x,
                                                    ushort4* __restrict__ o, int n4) {
  int stride = gridDim.x * blockDim.x;
  for (int i = blockIdx.x * blockDim.x + threadIdx.x; i < n4; i += stride) {
    float4 v = x[i];
    o[i] = make_ushort4(f2b(v.x), f2b(v.y), f2b(v.z), f2b(v.w));
  }
}

// ---------- kernel 2: W [K][N] fp32 -> Wt [N][K] bf16 ----------
__global__ __launch_bounds__(256) void transW_kernel(const float* __restrict__ W,
                                                     ushort_t* __restrict__ Wt) {
  __shared__ ushort_t tile[32][33];
  int tx = threadIdx.x;  // 0..31
  int ty = threadIdx.y;  // 0..7
  int n0 = blockIdx.x * 32;
  int k0 = blockIdx.y * 32;
#pragma unroll
  for (int r = 0; r < 4; r++) {
    int k = k0 + ty + r * 8;
    tile[ty + r * 8][tx] = f2b(W[(size_t)k * NN + n0 + tx]);
  }
  __syncthreads();
#pragma unroll
  for (int r = 0; r < 4; r++) {
    int n = n0 + ty + r * 8;
    Wt[(size_t)n * KK + k0 + tx] = tile[tx][ty + r * 8];
  }
}

// ---------- kernel 3: GEMM U = x @ W (+bias), sigmoid on f/r thirds, bf16 out ----------
// A: x_bf [M][K] bf16, Bt: Wt [N][K] bf16. 128x128 tile, BK=32, 4 waves 2x2.
__global__ __launch_bounds__(256) void gemm_kernel(const ushort_t* __restrict__ Abf,
                                                   const ushort_t* __restrict__ Btb,
                                                   const float* __restrict__ bias,
                                                   ushort_t* __restrict__ U) {
  __shared__ __align__(16) ushort_t As[128 * 32];
  __shared__ __align__(16) ushort_t Bs[128 * 32];
  const int tid = threadIdx.x;
  const int lane = tid & 63;
  const int wave = tid >> 6;
  const int wm = wave >> 1, wn = wave & 1;
  const int bn = blockIdx.x, bm = blockIdx.y;
  const int rowA0 = bm * 128, rowB0 = bn * 128;

  // staging: wave w fills rows [32w, 32w+32) of As and Bs; lane -> (row, 16B chunk)
  const int srow = wave * 32 + (lane >> 2);
  const int schunk = (lane & 3) * 8;  // ushort offset
  const ushort_t* gA = Abf + (size_t)(rowA0 + srow) * KK + schunk;
  const ushort_t* gB = Btb + (size_t)(rowB0 + srow) * KK + schunk;
  ushort_t* lA = As + wave * 32 * 32;  // wave-uniform
  ushort_t* lB = Bs + wave * 32 * 32;

  floatx4 acc[4][4];
#pragma unroll
  for (int i = 0; i < 4; i++)
#pragma unroll
    for (int j = 0; j < 4; j++) acc[i][j] = (floatx4){0.f, 0.f, 0.f, 0.f};

  const int m16 = lane & 15;
  const int q8 = (lane >> 4) * 8;
  const ushort_t* rA = As + (wm * 64 + m16) * 32 + q8;
  const ushort_t* rB = Bs + (wn * 64 + m16) * 32 + q8;

  for (int k0 = 0; k0 < KK; k0 += 32) {
    __syncthreads();
    async_ld16(gA + k0, lA);
    async_ld16(gA + 16 * KK + k0, lA + 16 * 32);
    async_ld16(gB + k0, lB);
    async_ld16(gB + 16 * KK + k0, lB + 16 * 32);
    __syncthreads();
    bf16x8 af[4], bfr[4];
#pragma unroll
    for (int i = 0; i < 4; i++) af[i] = *(const bf16x8*)(rA + i * 16 * 32);
#pragma unroll
    for (int j = 0; j < 4; j++) bfr[j] = *(const bf16x8*)(rB + j * 16 * 32);
#pragma unroll
    for (int i = 0; i < 4; i++)
#pragma unroll
      for (int j = 0; j < 4; j++)
        acc[i][j] = __builtin_amdgcn_mfma_f32_16x16x32_bf16(af[i], bfr[j], acc[i][j], 0, 0, 0);
  }

  // epilogue: C/D layout col = lane&15, row = (lane>>4)*4 + reg
  const int mode = bn >> 3;  // 0: x_tilde, 1: f, 2: r
  const int q4 = (lane >> 4) * 4;
#pragma unroll
  for (int j = 0; j < 4; j++) {
    int col = rowB0 + wn * 64 + j * 16 + m16;
    float bv = bias[col];
#pragma unroll
    for (int i = 0; i < 4; i++) {
      int row = rowA0 + wm * 64 + i * 16 + q4;
#pragma unroll
      for (int r = 0; r < 4; r++) {
        float v = acc[i][j][r] + bv;
        if (mode != 0) v = fast_sigmoid(v);
        U[(size_t)(row + r) * NN + col] = f2b(v);
      }
    }
  }
}

// ---------- kernel 4: per-chunk scan summaries (A = prod f, B = local c end) ----------
__global__ __launch_bounds__(256) void pass1_kernel(const ushort_t* __restrict__ U,
                                                    float* __restrict__ Asum,
                                                    float* __restrict__ Bsum) {
  int gid = blockIdx.x * 256 + threadIdx.x;  // 262144 threads
  int hp = gid & 511;
  int chunk = (gid >> 9) & 31;
  int b = gid >> 14;
  int row0 = b * TT + chunk * CLEN;
  const ushort_t* base = U + (size_t)row0 * NN;
  float c0 = 0.f, c1 = 0.f, A0 = 1.f, A1 = 1.f;
#pragma unroll 4
  for (int t = 0; t < CLEN; t++) {
    const ushort_t* p = base + (size_t)t * NN;
    uint_t xx = *(const uint_t*)(p + 2 * hp);
    uint_t ff = *(const uint_t*)(p + HH + 2 * hp);
    float x0 = b2f_lo(xx), x1 = b2f_hi(xx);
    float f0 = b2f_lo(ff), f1 = b2f_hi(ff);
    A0 *= f0; A1 *= f1;
    c0 = f0 * c0 + (1.f - f0) * x0;
    c1 = f1 * c1 + (1.f - f1) * x1;
  }
  int sidx = (b * NCHUNK + chunk) * 512 + hp;
  ((float2*)Asum)[sidx] = make_float2(A0, A1);
  ((float2*)Bsum)[sidx] = make_float2(c0, c1);
}

// ---------- kernel 5: sequential combine over chunk summaries ----------
__global__ __launch_bounds__(256) void fixup_kernel(const float* __restrict__ Asum,
                                                    const float* __restrict__ Bsum,
                                                    float* __restrict__ Cinit) {
  int gid = blockIdx.x * 256 + threadIdx.x;  // 16384
  int h = gid & 1023;
  int b = gid >> 10;
  float c = 0.f;
#pragma unroll
  for (int j = 0; j < NCHUNK; j++) {
    int idx = (b * NCHUNK + j) * HH + h;
    Cinit[idx] = c;
    c = Bsum[idx] + Asum[idx] * c;
  }
}

// ---------- kernel 6: final scan producing h ----------
__global__ __launch_bounds__(256) void pass3_kernel(const ushort_t* __restrict__ U,
                                                    const float* __restrict__ Cinit,
                                                    float* __restrict__ out) {
  int gid = blockIdx.x * 256 + threadIdx.x;  // 262144
  int hp = gid & 511;
  int chunk = (gid >> 9) & 31;
  int b = gid >> 14;
  int row0 = b * TT + chunk * CLEN;
  const ushort_t* base = U + (size_t)row0 * NN;
  int ci = (b * NCHUNK + chunk) * HH + 2 * hp;
  float c0 = Cinit[ci], c1 = Cinit[ci + 1];
  float2* o = (float2*)out;
#pragma unroll 4
  for (int t = 0; t < CLEN; t++) {
    const ushort_t* p = base + (size_t)t * NN;
    uint_t xx = *(const uint_t*)(p + 2 * hp);
    uint_t ff = *(const uint_t*)(p + HH + 2 * hp);
    uint_t rr = *(const uint_t*)(p + 2 * HH + 2 * hp);
    float x0 = b2f_lo(xx), x1 = b2f_hi(xx);
    float f0 = b2f_lo(ff), f1 = b2f_hi(ff);
    float r0 = b2f_lo(rr), r1 = b2f_hi(rr);
    c0 = f0 * c0 + (1.f - f0) * x0;
    c1 = f1 * c1 + (1.f - f1) * x1;
    float h0 = r0 * fast_tanh(c0) + (1.f - r0) * x0;
    float h1 = r1 * fast_tanh(c1) + (1.f - r1) * x1;
    o[(size_t)(row0 + t) * 512 + hp] = make_float2(h0, h1);
  }
}

extern "C" void kernel_launch(void* const* d_in, const int* in_sizes, int n_in,
                              void* d_out, int out_size, void* d_ws, size_t ws_size,
                              hipStream_t stream) {
  (void)in_sizes; (void)n_in; (void)out_size; (void)ws_size;
  const float* x = (const float*)d_in[0];
  const float* W = (const float*)d_in[1];
  const float* bias = (const float*)d_in[2];
  float* out = (float*)d_out;
  char* ws = (char*)d_ws;

  // workspace layout (total ~281 MB)
  ushort_t* x_bf = (ushort_t*)ws;                                     // 67,108,864 B
  ushort_t* Wt   = (ushort_t*)(ws + 67108864ull);                     //  6,291,456 B
  ushort_t* U    = (ushort_t*)(ws + 67108864ull + 6291456ull);        // 201,326,592 B
  float* Asum  = (float*)(ws + 274726912ull);                         //  2,097,152 B
  float* Bsum  = (float*)(ws + 276824064ull);                         //  2,097,152 B
  float* Cinit = (float*)(ws + 278921216ull);                         //  2,097,152 B

  cvt_x_kernel<<<1024, 256, 0, stream>>>((const float4*)x, (ushort4*)x_bf, MM * KK / 4);
  transW_kernel<<<dim3(NN / 32, KK / 32), dim3(32, 8), 0, stream>>>(W, Wt);
  gemm_kernel<<<dim3(NN / 128, MM / 128), 256, 0, stream>>>(x_bf, Wt, bias, U);
  pass1_kernel<<<1024, 256, 0, stream>>>(U, Asum, Bsum);
  fixup_kernel<<<64, 256, 0, stream>>>(Asum, Bsum, Cinit);
  pass3_kernel<<<1024, 256, 0, stream>>>(U, Cinit, out);
}